// Round 16
// baseline (265.011 us; speedup 1.0000x reference)
//
#include <hip/hip_runtime.h>

#define NNODES 50000
#define NEDGES 800000
#define ETOT   (NNODES + NEDGES)   // 850000 (edges + self loops)
#define NEG 0.2f
#define BKTS 196                   // coarse buckets of 256 nodes (49999>>8 = 195)
#define P1E 4096                   // edges per phase-1 block
#define NP1 ((ETOT + P1E - 1) / P1E)   // 208

typedef unsigned short ushort_t;
typedef unsigned int uint_t;
typedef __attribute__((ext_vector_type(8))) short short8;   // 8 bf16 (4 VGPRs)
typedef __attribute__((ext_vector_type(4))) float f32x4;    // 4 fp32 acc
typedef __attribute__((ext_vector_type(2))) float v2f;      // packed fp32 (v_pk_*)

__device__ __forceinline__ ushort_t f2bf(float f) {   // RTN bf16
  uint_t u = __float_as_uint(f);
  u += 0x7FFFu + ((u >> 16) & 1u);
  return (ushort_t)(u >> 16);
}
__device__ __forceinline__ float bf2f(ushort_t h) {
  return __uint_as_float((uint_t)h << 16);
}
__device__ __forceinline__ v2f unpk(uint_t u) {       // 2 bf16 -> v2f
  v2f r;
  r.x = __uint_as_float(u << 16);
  r.y = __uint_as_float(u & 0xffff0000u);
  return r;
}

// ---------------- CSR build: two-level LDS counting sort (atomic-free global) ----------------
__global__ __launch_bounds__(256) void coarse_hist(const int* __restrict__ ei,
                                                   int* __restrict__ pcnt) {
  __shared__ int c[BKTS];
  for (int i = threadIdx.x; i < BKTS; i += 256) c[i] = 0;
  __syncthreads();
  int e0 = blockIdx.x * P1E;
#pragma unroll
  for (int t = 0; t < P1E / 256; ++t) {
    int i = e0 + t * 256 + (int)threadIdx.x;
    if (i < ETOT) {
      int dst = (i < NEDGES) ? ei[NEDGES + i] : (i - NEDGES);
      atomicAdd(&c[dst >> 8], 1);
    }
  }
  __syncthreads();
  for (int i = threadIdx.x; i < BKTS; i += 256)
    pcnt[i * NP1 + blockIdx.x] = c[i];
}

__global__ __launch_bounds__(64) void coarse_scan(const int* __restrict__ pcnt,
                                                  int* __restrict__ goffArr,
                                                  int* __restrict__ tot) {
  int b = blockIdx.x;
  int lane = threadIdx.x;
  int carry = 0;
  for (int k0 = 0; k0 < NP1; k0 += 64) {
    int k = k0 + lane;
    int v = (k < NP1) ? pcnt[b * NP1 + k] : 0;
    int s = v;
    for (int off = 1; off < 64; off <<= 1) {
      int u = __shfl_up(s, off);
      if (lane >= off) s += u;
    }
    if (k < NP1) goffArr[b * NP1 + k] = carry + s - v;   // exclusive
    carry += __shfl(s, 63);
  }
  if (lane == 0) tot[b] = carry;
}

__global__ __launch_bounds__(256) void bucket_scan(const int* __restrict__ tot,
                                                   int* __restrict__ bucketStart,
                                                   int* __restrict__ rowptr) {
  if (threadIdx.x == 0) {
    int r = 0;
    for (int i = 0; i < BKTS; ++i) { bucketStart[i] = r; r += tot[i]; }
    bucketStart[BKTS] = r;          // == ETOT
    rowptr[NNODES] = ETOT;
  }
}

__global__ __launch_bounds__(256) void bin_phase1(const int* __restrict__ ei,
                                                  const int* __restrict__ bucketStart,
                                                  const int* __restrict__ goffArr,
                                                  uint_t* __restrict__ binned) {
  __shared__ int cnt[BKTS], pref[BKTS], fillL[BKTS];
  __shared__ uint_t stage[P1E];
  int e0 = blockIdx.x * P1E;
  for (int i = threadIdx.x; i < BKTS; i += 256) { cnt[i] = 0; fillL[i] = 0; }
  __syncthreads();
  uint_t mypk[P1E / 256];
  int mybkt[P1E / 256];
#pragma unroll
  for (int t = 0; t < P1E / 256; ++t) {
    int i = e0 + t * 256 + (int)threadIdx.x;
    if (i < ETOT) {
      int dst = (i < NEDGES) ? ei[NEDGES + i] : (i - NEDGES);
      int src = (i < NEDGES) ? ei[i] : dst;
      int b = dst >> 8;
      mypk[t] = (uint_t)src | ((uint_t)(dst & 255) << 16) | ((uint_t)b << 24);
      mybkt[t] = b;
      atomicAdd(&cnt[b], 1);
    } else mybkt[t] = -1;
  }
  __syncthreads();
  if (threadIdx.x == 0) {
    int r = 0;
    for (int b = 0; b < BKTS; ++b) { pref[b] = r; r += cnt[b]; }
  }
  __syncthreads();
#pragma unroll
  for (int t = 0; t < P1E / 256; ++t) {
    if (mybkt[t] >= 0) {
      int p = pref[mybkt[t]] + atomicAdd(&fillL[mybkt[t]], 1);
      stage[p] = mypk[t];
    }
  }
  __syncthreads();
  int total = (e0 + P1E <= ETOT) ? P1E : (ETOT - e0);
  for (int j = threadIdx.x; j < total; j += 256) {
    uint_t pk = stage[j];
    int b = pk >> 24;
    binned[bucketStart[b] + goffArr[b * NP1 + blockIdx.x] + (j - pref[b])] = pk;
  }
}

__global__ __launch_bounds__(256) void bin_phase2(const uint_t* __restrict__ binned,
                                                  const int* __restrict__ bucketStart,
                                                  int* __restrict__ rowptr,
                                                  int* __restrict__ csrc) {
  __shared__ int cnt[256], pref[256], fillL[256];
  __shared__ int outS[8192];       // max bucket ~4700; ample
  int b = blockIdx.x;
  int base = bucketStart[b];
  int cntAll = bucketStart[b + 1] - base;
  cnt[threadIdx.x] = 0; fillL[threadIdx.x] = 0;
  __syncthreads();
  for (int j = threadIdx.x; j < cntAll; j += 256)
    atomicAdd(&cnt[(binned[base + j] >> 16) & 255], 1);
  __syncthreads();
  if (threadIdx.x == 0) {
    int r = 0;
    for (int i = 0; i < 256; ++i) { pref[i] = r; r += cnt[i]; }
  }
  __syncthreads();
  int node = b * 256 + (int)threadIdx.x;
  if (node < NNODES) rowptr[node] = base + pref[threadIdx.x];
  for (int j = threadIdx.x; j < cntAll; j += 256) {
    uint_t pk = binned[base + j];
    int d = (pk >> 16) & 255;
    int p = pref[d] + atomicAdd(&fillL[d], 1);
    outS[p] = (int)(pk & 0xFFFF);
  }
  __syncthreads();
  for (int j = threadIdx.x; j < cntAll; j += 256)
    csrc[base + j] = outS[j];
}

// ---------------- W prep: transpose + split-bf16 [n][k] ----------------
__global__ __launch_bounds__(256) void prep_w(const float* __restrict__ Wl1,
                                              const float* __restrict__ Wr1,
                                              ushort_t* __restrict__ WtHi,
                                              ushort_t* __restrict__ WtLo) {
  int k = blockIdx.x;           // 0..127
  int n = threadIdx.x;          // 0..255 (concat col)
  float w = (n < 128) ? Wl1[k * 128 + n] : Wr1[k * 128 + (n - 128)];
  ushort_t h = f2bf(w);
  WtHi[n * 128 + k] = h;
  WtLo[n * 128 + k] = f2bf(w - bf2f(h));
}

// ---------------- GEMM1 via MFMA (split-bf16 = fp32-quality); gl1+gr1 both bf16 out ----------------
__global__ __launch_bounds__(256) void gemm1_mfma(
    const float* __restrict__ x,
    const ushort_t* __restrict__ WtHi, const ushort_t* __restrict__ WtLo,
    const float* __restrict__ bl1, const float* __restrict__ br1,
    ushort_t* __restrict__ gl1, ushort_t* __restrict__ gr1) {
  constexpr int LDA = 132;
  __shared__ __align__(16) char smem[32 * 260 * 4];   // Cs overlays Ahi/Alo
  ushort_t (*Ahi)[LDA] = (ushort_t(*)[LDA])smem;
  ushort_t (*Alo)[LDA] = (ushort_t(*)[LDA])(smem + 32 * LDA * 2);
  float (*Cs)[260] = (float(*)[260])smem;
  int m0 = blockIdx.x * 32;
  int tid = threadIdx.x;
#pragma unroll
  for (int i = 0; i < 4; ++i) {
    int it = i * 256 + tid;
    int row = it >> 5, c4 = it & 31;
    int gm = m0 + row;
    float4 v = (gm < NNODES) ? *(const float4*)&x[(size_t)gm * 128 + 4 * c4]
                             : make_float4(0.f, 0.f, 0.f, 0.f);
    ushort_t h0 = f2bf(v.x), h1 = f2bf(v.y), h2 = f2bf(v.z), h3 = f2bf(v.w);
    ushort_t l0 = f2bf(v.x - bf2f(h0)), l1 = f2bf(v.y - bf2f(h1));
    ushort_t l2 = f2bf(v.z - bf2f(h2)), l3 = f2bf(v.w - bf2f(h3));
    uint2 ph, pl;
    ph.x = (uint_t)h0 | ((uint_t)h1 << 16); ph.y = (uint_t)h2 | ((uint_t)h3 << 16);
    pl.x = (uint_t)l0 | ((uint_t)l1 << 16); pl.y = (uint_t)l2 | ((uint_t)l3 << 16);
    *(uint2*)&Ahi[row][4 * c4] = ph;
    *(uint2*)&Alo[row][4 * c4] = pl;
  }
  __syncthreads();
  int wave = tid >> 6, lane = tid & 63;
  int quad = lane >> 4, nl = lane & 15;
  int nb = wave * 64;
  f32x4 acc[2][4];
#pragma unroll
  for (int tm = 0; tm < 2; ++tm)
#pragma unroll
    for (int tn = 0; tn < 4; ++tn) acc[tm][tn] = (f32x4){0.f, 0.f, 0.f, 0.f};

#pragma unroll
  for (int kc = 0; kc < 4; ++kc) {
    int klane = kc * 32 + quad * 8;
    short8 ah[2], al[2], bh[4], bl[4];
#pragma unroll
    for (int tm = 0; tm < 2; ++tm) {
      ah[tm] = *(const short8*)&Ahi[16 * tm + nl][klane];
      al[tm] = *(const short8*)&Alo[16 * tm + nl][klane];
    }
#pragma unroll
    for (int tn = 0; tn < 4; ++tn) {
      size_t wo = (size_t)(nb + 16 * tn + nl) * 128 + klane;
      bh[tn] = *(const short8*)&WtHi[wo];
      bl[tn] = *(const short8*)&WtLo[wo];
    }
#pragma unroll
    for (int tm = 0; tm < 2; ++tm)
#pragma unroll
      for (int tn = 0; tn < 4; ++tn) {
        acc[tm][tn] = __builtin_amdgcn_mfma_f32_16x16x32_bf16(ah[tm], bh[tn], acc[tm][tn], 0, 0, 0);
        acc[tm][tn] = __builtin_amdgcn_mfma_f32_16x16x32_bf16(ah[tm], bl[tn], acc[tm][tn], 0, 0, 0);
        acc[tm][tn] = __builtin_amdgcn_mfma_f32_16x16x32_bf16(al[tm], bh[tn], acc[tm][tn], 0, 0, 0);
      }
  }
  float bb[4];
#pragma unroll
  for (int tn = 0; tn < 4; ++tn) {
    int n = nb + 16 * tn + nl;
    bb[tn] = (n < 128) ? bl1[n] : br1[n - 128];
  }
  __syncthreads();   // all A-tile reads done before Cs overlays the same LDS
#pragma unroll
  for (int tm = 0; tm < 2; ++tm)
#pragma unroll
    for (int tn = 0; tn < 4; ++tn)
#pragma unroll
      for (int r = 0; r < 4; ++r)
        Cs[16 * tm + 4 * quad + r][nb + 16 * tn + nl] = acc[tm][tn][r] + bb[tn];
  __syncthreads();
#pragma unroll
  for (int i = 0; i < 2; ++i) {     // gl1 (cols 0..127, bf16)
    int it = i * 256 + tid;
    int row = it >> 4, oc = (it & 15) * 8;
    int gm = m0 + row;
    if (gm < NNODES) {
      uint4 pk;
      pk.x = (uint_t)f2bf(Cs[row][oc + 0]) | ((uint_t)f2bf(Cs[row][oc + 1]) << 16);
      pk.y = (uint_t)f2bf(Cs[row][oc + 2]) | ((uint_t)f2bf(Cs[row][oc + 3]) << 16);
      pk.z = (uint_t)f2bf(Cs[row][oc + 4]) | ((uint_t)f2bf(Cs[row][oc + 5]) << 16);
      pk.w = (uint_t)f2bf(Cs[row][oc + 6]) | ((uint_t)f2bf(Cs[row][oc + 7]) << 16);
      *(uint4*)&gl1[(size_t)gm * 128 + oc] = pk;
    }
  }
#pragma unroll
  for (int i = 0; i < 2; ++i) {     // gr1 (cols 128..255, bf16)
    int it = i * 256 + tid;
    int row = it >> 4, oc = (it & 15) * 8;
    int gm = m0 + row;
    if (gm < NNODES) {
      uint4 pk;
      pk.x = (uint_t)f2bf(Cs[row][128 + oc + 0]) | ((uint_t)f2bf(Cs[row][128 + oc + 1]) << 16);
      pk.y = (uint_t)f2bf(Cs[row][128 + oc + 2]) | ((uint_t)f2bf(Cs[row][128 + oc + 3]) << 16);
      pk.z = (uint_t)f2bf(Cs[row][128 + oc + 4]) | ((uint_t)f2bf(Cs[row][128 + oc + 5]) << 16);
      pk.w = (uint_t)f2bf(Cs[row][128 + oc + 6]) | ((uint_t)f2bf(Cs[row][128 + oc + 7]) << 16);
      *(uint4*)&gr1[(size_t)gm * 128 + oc] = pk;
    }
  }
}

// ---------------- GEMM2: bf16 h in, bf16 gl2/gr2 out (fp32 compute) ----------------
__global__ __launch_bounds__(128) void gemm2_tile(
    const ushort_t* __restrict__ A,               // h, bf16 [N][128]
    const float* __restrict__ W1, const float* __restrict__ b1,
    const float* __restrict__ W2, const float* __restrict__ b2,
    ushort_t* __restrict__ G1, ushort_t* __restrict__ G2) {
  constexpr int K = 128, KC = 32, BM = 128, BN = 64, MCOLS = 32, NT = 128;
  constexpr int LDA = BM + 4;
  __shared__ float AsT[KC][LDA];
  __shared__ float Ws[KC][BN];
  int row0 = blockIdx.x * BM;
  int tid = threadIdx.x;
  int tx = tid % (BN / 8), ty = tid / (BN / 8);
  float acc[8][8];
#pragma unroll
  for (int i = 0; i < 8; ++i)
#pragma unroll
    for (int j = 0; j < 8; ++j) acc[i][j] = 0.f;

  for (int kc = 0; kc < K; kc += KC) {
#pragma unroll
    for (int item = tid; item < BM * (KC / 4); item += NT) {
      int r = item >> 3, f4 = item & 7;
      int grow = row0 + r;
      uint2 u = (grow < NNODES)
          ? *(const uint2*)&A[(size_t)grow * K + kc + 4 * f4]
          : make_uint2(0u, 0u);
      AsT[4 * f4 + 0][r] = __uint_as_float(u.x << 16);
      AsT[4 * f4 + 1][r] = __uint_as_float(u.x & 0xffff0000u);
      AsT[4 * f4 + 2][r] = __uint_as_float(u.y << 16);
      AsT[4 * f4 + 3][r] = __uint_as_float(u.y & 0xffff0000u);
    }
#pragma unroll
    for (int item = tid; item < KC * (BN / 4); item += NT) {
      int k = item / (BN / 4), c4 = item % (BN / 4);
      int ccat = 4 * c4;
      const float* src = (ccat < MCOLS)
          ? &W1[(size_t)(kc + k) * MCOLS + ccat]
          : &W2[(size_t)(kc + k) * MCOLS + ccat - MCOLS];
      *(float4*)&Ws[k][4 * c4] = *(const float4*)src;
    }
    __syncthreads();
#pragma unroll 8
    for (int k = 0; k < KC; ++k) {
      float4 a0 = *(const float4*)&AsT[k][4 * ty];
      float4 a1 = *(const float4*)&AsT[k][BM / 2 + 4 * ty];
      float4 w0 = *(const float4*)&Ws[k][4 * tx];
      float4 w1 = *(const float4*)&Ws[k][BN / 2 + 4 * tx];
      float av[8] = {a0.x, a0.y, a0.z, a0.w, a1.x, a1.y, a1.z, a1.w};
      float wv[8] = {w0.x, w0.y, w0.z, w0.w, w1.x, w1.y, w1.z, w1.w};
#pragma unroll
      for (int i = 0; i < 8; ++i)
#pragma unroll
        for (int j = 0; j < 8; ++j) acc[i][j] = fmaf(av[i], wv[j], acc[i][j]);
    }
    __syncthreads();
  }
#pragma unroll
  for (int i = 0; i < 8; ++i) {
    int row = row0 + (i < 4 ? 4 * ty + i : BM / 2 + 4 * ty + (i - 4));
    if (row >= NNODES) continue;
#pragma unroll
    for (int jj = 0; jj < 2; ++jj) {
      int ccat = (jj == 0 ? 4 * tx : BN / 2 + 4 * tx);
      float o0 = acc[i][4 * jj + 0], o1 = acc[i][4 * jj + 1];
      float o2 = acc[i][4 * jj + 2], o3 = acc[i][4 * jj + 3];
      if (ccat < MCOLS) {
        float4 bb = *(const float4*)&b1[ccat];
        uint2 pk;
        pk.x = (uint_t)f2bf(o0 + bb.x) | ((uint_t)f2bf(o1 + bb.y) << 16);
        pk.y = (uint_t)f2bf(o2 + bb.z) | ((uint_t)f2bf(o3 + bb.w) << 16);
        *(uint2*)&G1[(size_t)row * MCOLS + ccat] = pk;
      } else {
        int c = ccat - MCOLS;
        float4 bb = *(const float4*)&b2[c];
        uint2 pk;
        pk.x = (uint_t)f2bf(o0 + bb.x) | ((uint_t)f2bf(o1 + bb.y) << 16);
        pk.y = (uint_t)f2bf(o2 + bb.z) | ((uint_t)f2bf(o3 + bb.w) << 16);
        *(uint2*)&G2[(size_t)row * MCOLS + c] = pk;
      }
    }
  }
}

// ---------------- layer 1: wave/node, 16 lanes/edge, packed-fp32 (v_pk_*) channel math ----------------
__global__ __launch_bounds__(256) void gat1_edge(const int* __restrict__ rowptr,
                          const int* __restrict__ csrc,
                          const ushort_t* __restrict__ glb,    // bf16 table [N][128]
                          const ushort_t* __restrict__ grb,    // bf16 [N][128]
                          const float* __restrict__ att, const float* __restrict__ bias,
                          ushort_t* __restrict__ hout) {       // bf16 [N][128]
  int node = blockIdx.x * 4 + (threadIdx.x >> 6);
  if (node >= NNODES) return;
  int lane = threadIdx.x & 63;
  int eslot = lane >> 4;        // 4 edge slots
  int q = lane & 15;            // 16 lanes per edge; lane covers 8 channels
  int c8 = q * 8;               // head = q>>2
  float4 a04 = *(const float4*)(att + c8);
  float4 a14 = *(const float4*)(att + c8 + 4);
  v2f av0 = {a04.x, a04.y}, av1 = {a04.z, a04.w};
  v2f av2 = {a14.x, a14.y}, av3 = {a14.z, a14.w};
  uint4 ug = *(const uint4*)(grb + (size_t)node * 128 + c8);
  v2f gr0 = unpk(ug.x), gr1 = unpk(ug.y), gr2 = unpk(ug.z), gr3 = unpk(ug.w);
  const v2f neg2 = {NEG, NEG};
  int start = rowptr[node], end = rowptr[node + 1];
  float denom = 0.f;
  v2f A0 = {0.f, 0.f}, A1 = {0.f, 0.f}, A2 = {0.f, 0.f}, A3 = {0.f, 0.f};
  for (int b = start; b < end; b += 64) {
    int nb = end - b; if (nb > 64) nb = 64;
    int sidx = (lane < nb) ? csrc[b + lane] : 0;
    for (int j = 0; j < nb; j += 4) {
      bool pv = (j + eslot) < nb;
      int s = __shfl(sidx, j + eslot);
      uint4 up = *(const uint4*)(glb + (size_t)s * 128 + c8);  // 8 bf16 channels
      v2f g0 = unpk(up.x), g1 = unpk(up.y), g2 = unpk(up.z), g3 = unpk(up.w);
      v2f t, d;
      t = g0 + gr0; t = __builtin_elementwise_max(t, t * neg2); d = t * av0;
      t = g1 + gr1; t = __builtin_elementwise_max(t, t * neg2); d += t * av1;
      t = g2 + gr2; t = __builtin_elementwise_max(t, t * neg2); d += t * av2;
      t = g3 + gr3; t = __builtin_elementwise_max(t, t * neg2); d += t * av3;
      float v = d.x + d.y;
      v += __shfl_xor(v, 1); v += __shfl_xor(v, 2);   // e[head] over 4 lanes (32 ch)
      float ex = pv ? __expf(v) : 0.f;                // |e| bounded: max-free softmax
      denom += ex;
      v2f exv = {ex, ex};
      A0 += exv * g0; A1 += exv * g1; A2 += exv * g2; A3 += exv * g3;
    }
  }
  denom += __shfl_xor(denom, 16); denom += __shfl_xor(denom, 32);
  A0.x += __shfl_xor(A0.x, 16); A0.x += __shfl_xor(A0.x, 32);
  A0.y += __shfl_xor(A0.y, 16); A0.y += __shfl_xor(A0.y, 32);
  A1.x += __shfl_xor(A1.x, 16); A1.x += __shfl_xor(A1.x, 32);
  A1.y += __shfl_xor(A1.y, 16); A1.y += __shfl_xor(A1.y, 32);
  A2.x += __shfl_xor(A2.x, 16); A2.x += __shfl_xor(A2.x, 32);
  A2.y += __shfl_xor(A2.y, 16); A2.y += __shfl_xor(A2.y, 32);
  A3.x += __shfl_xor(A3.x, 16); A3.x += __shfl_xor(A3.x, 32);
  A3.y += __shfl_xor(A3.y, 16); A3.y += __shfl_xor(A3.y, 32);
  float inv = 1.f / denom;
  if (eslot == 0) {
    float4 bv = *(const float4*)(bias + c8);
    float o0 = A0.x * inv + bv.x, o1 = A0.y * inv + bv.y;
    float o2 = A1.x * inv + bv.z, o3 = A1.y * inv + bv.w;
    o0 = o0 > 0.f ? o0 : __expf(o0) - 1.f;   // ELU
    o1 = o1 > 0.f ? o1 : __expf(o1) - 1.f;
    o2 = o2 > 0.f ? o2 : __expf(o2) - 1.f;
    o3 = o3 > 0.f ? o3 : __expf(o3) - 1.f;
    uint2 pk;
    pk.x = (uint_t)f2bf(o0) | ((uint_t)f2bf(o1) << 16);
    pk.y = (uint_t)f2bf(o2) | ((uint_t)f2bf(o3) << 16);
    *(uint2*)&hout[(size_t)node * 128 + c8] = pk;
  } else if (eslot == 1) {
    float4 bv = *(const float4*)(bias + c8 + 4);
    float o0 = A2.x * inv + bv.x, o1 = A2.y * inv + bv.y;
    float o2 = A3.x * inv + bv.z, o3 = A3.y * inv + bv.w;
    o0 = o0 > 0.f ? o0 : __expf(o0) - 1.f;
    o1 = o1 > 0.f ? o1 : __expf(o1) - 1.f;
    o2 = o2 > 0.f ? o2 : __expf(o2) - 1.f;
    o3 = o3 > 0.f ? o3 : __expf(o3) - 1.f;
    uint2 pk;
    pk.x = (uint_t)f2bf(o0) | ((uint_t)f2bf(o1) << 16);
    pk.y = (uint_t)f2bf(o2) | ((uint_t)f2bf(o3) << 16);
    *(uint2*)&hout[(size_t)node * 128 + c8 + 4] = pk;
  }
}

// ---------------- layer 2: wave/node, 8 lanes/edge, packed-fp32 channel math ----------------
__global__ __launch_bounds__(256) void gat2_edge(const int* __restrict__ rowptr,
                          const int* __restrict__ csrc,
                          const ushort_t* __restrict__ gl, const ushort_t* __restrict__ gr,
                          const float* __restrict__ att, const float* __restrict__ bias,
                          float* __restrict__ out) {
  int node = blockIdx.x * 4 + (threadIdx.x >> 6);
  if (node >= NNODES) return;
  int lane = threadIdx.x & 63;
  int eslot = lane >> 3;        // 8 edge slots
  int q = lane & 7;             // 8 lanes per edge, 4 ch each
  int c4 = q * 4;
  float4 a4 = *(const float4*)(att + c4);
  v2f av0 = {a4.x, a4.y}, av1 = {a4.z, a4.w};
  uint2 ugr = *(const uint2*)(gr + (size_t)node * 32 + c4);
  v2f gr0 = unpk(ugr.x), gr1 = unpk(ugr.y);
  const v2f neg2 = {NEG, NEG};
  int start = rowptr[node], end = rowptr[node + 1];
  float denom = 0.f;
  v2f A0 = {0.f, 0.f}, A1 = {0.f, 0.f};
  for (int b = start; b < end; b += 64) {
    int nb = end - b; if (nb > 64) nb = 64;
    int sidx = (lane < nb) ? csrc[b + lane] : 0;
    for (int j = 0; j < nb; j += 8) {
      bool pv = (j + eslot) < nb;
      int s = __shfl(sidx, j + eslot);
      uint2 ugg = *(const uint2*)(gl + (size_t)s * 32 + c4);
      v2f g0 = unpk(ugg.x), g1 = unpk(ugg.y);
      v2f t, d;
      t = g0 + gr0; t = __builtin_elementwise_max(t, t * neg2); d = t * av0;
      t = g1 + gr1; t = __builtin_elementwise_max(t, t * neg2); d += t * av1;
      float v = d.x + d.y;
      v += __shfl_xor(v, 1); v += __shfl_xor(v, 2); v += __shfl_xor(v, 4);
      float ex = pv ? __expf(v) : 0.f;
      denom += ex;
      v2f exv = {ex, ex};
      A0 += exv * g0; A1 += exv * g1;
    }
  }
  denom += __shfl_xor(denom, 8); denom += __shfl_xor(denom, 16); denom += __shfl_xor(denom, 32);
  A0.x += __shfl_xor(A0.x, 8); A0.x += __shfl_xor(A0.x, 16); A0.x += __shfl_xor(A0.x, 32);
  A0.y += __shfl_xor(A0.y, 8); A0.y += __shfl_xor(A0.y, 16); A0.y += __shfl_xor(A0.y, 32);
  A1.x += __shfl_xor(A1.x, 8); A1.x += __shfl_xor(A1.x, 16); A1.x += __shfl_xor(A1.x, 32);
  A1.y += __shfl_xor(A1.y, 8); A1.y += __shfl_xor(A1.y, 16); A1.y += __shfl_xor(A1.y, 32);
  if (eslot == 0) {
    float4 bv = *(const float4*)(bias + c4);
    float inv = 1.f / denom;
    float4 o;
    o.x = A0.x * inv + bv.x; o.y = A0.y * inv + bv.y;
    o.z = A1.x * inv + bv.z; o.w = A1.y * inv + bv.w;
    *(float4*)(out + (size_t)node * 32 + c4) = o;
  }
}

extern "C" void kernel_launch(void* const* d_in, const int* in_sizes, int n_in,
                              void* d_out, int out_size, void* d_ws, size_t ws_size,
                              hipStream_t stream) {
  const float* x     = (const float*)d_in[0];
  const int*   ei    = (const int*)  d_in[1];
  const float* Wl1   = (const float*)d_in[2];
  const float* bl1   = (const float*)d_in[3];
  const float* Wr1   = (const float*)d_in[4];
  const float* br1   = (const float*)d_in[5];
  const float* att1  = (const float*)d_in[6];
  const float* bias1 = (const float*)d_in[7];
  const float* Wl2   = (const float*)d_in[8];
  const float* bl2   = (const float*)d_in[9];
  const float* Wr2   = (const float*)d_in[10];
  const float* br2   = (const float*)d_in[11];
  const float* att2  = (const float*)d_in[12];
  const float* bias2 = (const float*)d_in[13];
  float* out = (float*)d_out;

  char* w = (char*)d_ws;
  auto carve = [&](size_t bytes) {
    char* p = w;
    w += (bytes + 255) & ~(size_t)255;
    return p;
  };
  ushort_t* gl1 = (ushort_t*)carve((size_t)NNODES * 128 * 2);   // bf16 gather table
  ushort_t* gr1 = (ushort_t*)carve((size_t)NNODES * 128 * 2);   // bf16
  ushort_t* h   = (ushort_t*)carve((size_t)NNODES * 128 * 2);   // bf16
  ushort_t* gl2 = (ushort_t*)carve((size_t)NNODES * 32 * 2);    // bf16 (fits XCD L2)
  ushort_t* gr2 = (ushort_t*)carve((size_t)NNODES * 32 * 2);    // bf16
  ushort_t* WtHi = (ushort_t*)carve((size_t)256 * 128 * 2);
  ushort_t* WtLo = (ushort_t*)carve((size_t)256 * 128 * 2);
  int* pcnt    = (int*)carve((size_t)NP1 * BKTS * 4);
  int* goffArr = (int*)carve((size_t)NP1 * BKTS * 4);
  int* tot     = (int*)carve((size_t)BKTS * 4);
  int* bucketStart = (int*)carve((size_t)(BKTS + 1) * 4);
  int* rowptr = (int*)carve((size_t)(NNODES + 1) * 4);
  uint_t* binned = (uint_t*)carve((size_t)ETOT * 4);
  int* csrc = (int*)carve((size_t)ETOT * 4);

  prep_w<<<128, 256, 0, stream>>>(Wl1, Wr1, WtHi, WtLo);
  coarse_hist<<<NP1, 256, 0, stream>>>(ei, pcnt);
  coarse_scan<<<BKTS, 64, 0, stream>>>(pcnt, goffArr, tot);
  bucket_scan<<<1, 256, 0, stream>>>(tot, bucketStart, rowptr);
  bin_phase1<<<NP1, 256, 0, stream>>>(ei, bucketStart, goffArr, binned);
  bin_phase2<<<BKTS, 256, 0, stream>>>(binned, bucketStart, rowptr, csrc);

  gemm1_mfma<<<(NNODES + 31) / 32, 256, 0, stream>>>(x, WtHi, WtLo, bl1, br1, gl1, gr1);
  gat1_edge<<<(NNODES + 3) / 4, 256, 0, stream>>>(rowptr, csrc, gl1, gr1, att1, bias1, h);
  gemm2_tile<<<(NNODES + 127) / 128, 128, 0, stream>>>(h, Wl2, bl2, Wr2, br2, gl2, gr2);
  gat2_edge<<<(NNODES + 3) / 4, 256, 0, stream>>>(rowptr, csrc, gl2, gr2, att2, bias2, out);
}